// Round 3
// baseline (1123.569 us; speedup 1.0000x reference)
//
#include <hip/hip_runtime.h>
#include <hip/hip_bf16.h>
#include <cstdint>
#include <cstddef>

#define TOKENS   32768
#define DDIM     4096
#define NEXP     64
#define N2       65536       // TOKENS*2 slots
#define CAPACITY 1126        // int(32768*1.1*2/64)
#define KSPLIT   4
#define KQ       (DDIM / KSPLIT)   // 1024 k per wave
#define BK       32

// ---------------- workspace byte offsets ----------------
// part    : float[4][TOKENS][64] partial logits            @ 0       (32 MiB)
// p_flat  : float[N2]                                      @ 32 MiB
// e_flat  : int[N2]                                        @ +256 KiB
// psum    : float[64]                                      @ +512 KiB
// counts  : int[64]                                        @ +512 KiB + 256 B
// Wt      : float[4096][64] (W transposed)                 @ 34 MiB  (1 MiB)
#define WS_PART  0
#define WS_PFLAT (32u << 20)
#define WS_EFLAT ((32u << 20) + 262144u)
#define WS_PSUM  ((32u << 20) + 524288u)
#define WS_CNT   ((32u << 20) + 524288u + 256u)
#define WS_WT    (34u << 20)

// ---------------- zero dispatch+combine and psum ----------------
__global__ void zero_kernel(float* __restrict__ dc, float* __restrict__ psum) {
    int idx = blockIdx.x * blockDim.x + threadIdx.x;
    float4 z = make_float4(0.f, 0.f, 0.f, 0.f);
    const int n4 = (2 * TOKENS * NEXP) / 4;   // dispatch+combine contiguous
    for (int i = idx; i < n4; i += gridDim.x * blockDim.x)
        ((float4*)dc)[i] = z;
    if (idx < NEXP) psum[idx] = 0.f;
}

// ---------------- W transpose: Wt[d][e] = W[e][d] ----------------
// 64 blocks x 256 thr; block handles d-tile of 64. LDS tile transpose,
// coalesced read of W rows, coalesced 256B-row writes of Wt.
__global__ void wtrans_kernel(const float* __restrict__ W, float* __restrict__ Wt) {
    __shared__ float T[64][65];
    const int tid = threadIdx.x;
    const int d0  = blockIdx.x * 64;
    {
        int e = tid & 63, ip = tid >> 6;
#pragma unroll
        for (int jj = 0; jj < 4; ++jj) {
            int j = ip * 4 + jj;                  // float4 index 0..15
            float4 v = *(const float4*)&W[(size_t)e * DDIM + d0 + j * 4];
            T[e][j * 4 + 0] = v.x; T[e][j * 4 + 1] = v.y;
            T[e][j * 4 + 2] = v.z; T[e][j * 4 + 3] = v.w;
        }
    }
    __syncthreads();
    {
        int r = tid >> 2, eg = tid & 3;
#pragma unroll
        for (int mm = 0; mm < 4; ++mm) {
            int e0 = eg * 16 + mm * 4;
            float4 v = make_float4(T[e0][r], T[e0 + 1][r], T[e0 + 2][r], T[e0 + 3][r]);
            *(float4*)&Wt[(size_t)(d0 + r) * 64 + e0] = v;
        }
    }
}

// ---------------- logits GEMM, SGPR-W / lane=token ----------------
// grid = 1024 (512 token-groups x 2 wave-pairs), block = 128 thr (2 waves),
// 4 blocks/CU = 8 waves/CU. Wave = 64 tokens (lane=token) x 64 experts x
// one k-quarter (1024). W operand is wave-uniform -> scalar loads of
// Wt[k][0..63] (L2-resident 1 MiB), used directly as the SGPR operand of
// v_fmac_f32: zero LDS and zero VGPR cost for W. x staged in wave-PRIVATE
// LDS double-buffers via global_load_lds (8 instrs/chunk), read per-lane-row
// with XOR swizzle (col 16B-granule ^= row&7; staging pre-swizzles the
// global source, LDS dest stays linear). DS demand ~190cyc of a 4096cyc
// chunk (was ~6-9k: the old (m+n) b128 broadcast structure was DS-bound).
// NO barriers anywhere: waves fully independent, vmcnt-counted sync only.
// vmcnt(8) after issuing next chunk's 8 loads retires exactly the current
// chunk's 8 (in-order count); safe even if W loads fell back to VMEM since
// the wait precedes this iter's W loads and prior iters' were consumed.
__global__ __launch_bounds__(128, 2)
void gemm_logits(const float* __restrict__ x, const float* __restrict__ Wt,
                 float* __restrict__ part) {
    __shared__ __align__(16) float xb[2][2][2048];   // [wave][buf][64*32] = 32 KiB

    const int tid  = threadIdx.x;
    const int lane = tid & 63;
    const int wv   = tid >> 6;                                  // 0..1
    const int wvu  = __builtin_amdgcn_readfirstlane(wv);        // uniform
    const int qu   = __builtin_amdgcn_readfirstlane((blockIdx.x & 1) * 2 + wv);
    const int tb   = (blockIdx.x >> 1) * 64;                    // token base
    const int t    = tb + lane;                                 // lane's token
    const int k0   = qu * KQ;

    const int sr = lane >> 3;    // staging row-within-8
    const int sc = lane & 7;     // staging 16B granule

    auto stage = [&](int p, int c) {
#pragma unroll
        for (int i = 0; i < 8; ++i) {
            int r = i * 8 + sr;                                 // token row 0..63
            const float* g = x + (size_t)(tb + r) * DDIM + k0 + c * BK
                               + 4 * (sc ^ (r & 7));            // pre-swizzled src
            __builtin_amdgcn_global_load_lds(
                (const __attribute__((address_space(1))) void*)g,
                (__attribute__((address_space(3))) void*)&xb[wvu][p][i * 256],
                16, 0, 0);
        }
    };

    float acc[64];
#pragma unroll
    for (int e = 0; e < 64; ++e) acc[e] = 0.f;

    stage(0, 0);

    const int NCHUNK = KQ / BK;   // 32
    for (int c = 0; c < NCHUNK; ++c) {
        const int p = c & 1;
        if (c + 1 < NCHUNK) {
            stage(p ^ 1, c + 1);
            asm volatile("s_waitcnt vmcnt(8)" ::: "memory");
        } else {
            asm volatile("s_waitcnt vmcnt(0)" ::: "memory");
        }
        __builtin_amdgcn_sched_barrier(0);

        const float* __restrict__ wrow = Wt + (size_t)(k0 + c * BK) * 64;
#pragma unroll 2
        for (int k4 = 0; k4 < 8; ++k4) {
            float4 xr = *(const float4*)&xb[wvu][p][lane * 32 + 4 * (k4 ^ (lane & 7))];
#pragma unroll
            for (int kk = 0; kk < 4; ++kk) {
                float xv = (kk == 0) ? xr.x : (kk == 1) ? xr.y : (kk == 2) ? xr.z : xr.w;
                const float* __restrict__ wr = wrow + (k4 * 4 + kk) * 64;
#pragma unroll
                for (int e = 0; e < 64; ++e)
                    acc[e] = fmaf(xv, wr[e], acc[e]);
            }
        }
    }

    // epilogue: part[qu][t][0..63] — 16 float4 stores, write-combined in L2
    float* o = part + ((size_t)qu * TOKENS + t) * 64;
#pragma unroll
    for (int e4 = 0; e4 < 16; ++e4)
        *(float4*)&o[e4 * 4] =
            make_float4(acc[e4 * 4 + 0], acc[e4 * 4 + 1],
                        acc[e4 * 4 + 2], acc[e4 * 4 + 3]);
}

// ---------------- combine partials + softmax + top2 + probs + psum ---------
// 256 blocks x 256 threads; block handles 128 tokens. Sums 4 k-quarters.
__launch_bounds__(256, 2)
__global__ void combine_kernel(const float* __restrict__ part,
                               float* __restrict__ probs_out,
                               float* __restrict__ p_flat,
                               int* __restrict__ e_flat,
                               float* __restrict__ psum) {
    __shared__ __align__(16) float L[128][68];
    __shared__ float red[256];
    const int tid  = threadIdx.x;
    const int tok0 = blockIdx.x * 128;
    const size_t base = (size_t)tok0 * 64;

#pragma unroll
    for (int i = 0; i < 8; ++i) {
        int idx4 = i * 256 + tid;                 // float4 index in 8192-float slab
        float4 a0 = ((const float4*)(part + 0ull * TOKENS * 64 + base))[idx4];
        float4 a1 = ((const float4*)(part + 1ull * TOKENS * 64 + base))[idx4];
        float4 a2 = ((const float4*)(part + 2ull * TOKENS * 64 + base))[idx4];
        float4 a3 = ((const float4*)(part + 3ull * TOKENS * 64 + base))[idx4];
        float4 s = make_float4((a0.x + a1.x) + (a2.x + a3.x),
                               (a0.y + a1.y) + (a2.y + a3.y),
                               (a0.z + a1.z) + (a2.z + a3.z),
                               (a0.w + a1.w) + (a2.w + a3.w));
        int row = idx4 >> 4, col = (idx4 & 15) * 4;
        *(float4*)&L[row][col] = s;
    }
    __syncthreads();

    if (tid < 128) {
        const int t = tid;
        float m = -INFINITY;
#pragma unroll
        for (int e = 0; e < 64; ++e) m = fmaxf(m, L[t][e]);
        float s = 0.f;
#pragma unroll
        for (int e = 0; e < 64; ++e) {
            float v = expf(L[t][e] - m);
            L[t][e] = v;
            s += v;
        }
        float p1 = -1.f, p2 = -1.f; int i1 = 0, i2 = 0;
#pragma unroll
        for (int e = 0; e < 64; ++e) {
            float p = L[t][e] / s;
            L[t][e] = p;
            if (p > p1)      { p2 = p1; i2 = i1; p1 = p; i1 = e; }
            else if (p > p2) { p2 = p;  i2 = e; }
        }
        float rs = p1 + p2;
        int g = tok0 + t;
        p_flat[2 * g]     = p1 / rs;
        p_flat[2 * g + 1] = p2 / rs;
        e_flat[2 * g]     = i1;
        e_flat[2 * g + 1] = i2;
    }
    __syncthreads();

    // coalesced probs write
#pragma unroll
    for (int i = 0; i < 8; ++i) {
        int idx4 = i * 256 + tid;
        int row = idx4 >> 4, col = (idx4 & 15) * 4;
        ((float4*)(probs_out + base))[idx4] = *(const float4*)&L[row][col];
    }

    // per-expert column partial sums
    float acc = 0.f;
    {
        int e = tid & 63, rg = (tid >> 6) * 32;
#pragma unroll
        for (int r = 0; r < 32; ++r) acc += L[rg + r][e];
    }
    red[tid] = acc;
    __syncthreads();
    if (tid < 64) {
        float v = red[tid] + red[tid + 64] + red[tid + 128] + red[tid + 192];
        atomicAdd(&psum[tid], v);
    }
}

// ---------------- per-expert capacity ranking + scatter ----------------
// 64 blocks (one per expert) x 256 threads. If n <= CAPACITY every assigned
// slot is kept -> skip the sort (the common case: counts ~ 1024 +- 32).
__launch_bounds__(256, 2)
__global__ void expert_sort_kernel(const float* __restrict__ p_flat,
                                   const int* __restrict__ e_flat,
                                   float* __restrict__ dispatch,
                                   float* __restrict__ combine,
                                   int* __restrict__ counts) {
    __shared__ unsigned long long keys[4096];
    __shared__ int cnt;
    const int tid = threadIdx.x;
    const int e   = blockIdx.x;

    if (tid == 0) cnt = 0;
    __syncthreads();

    for (int i4 = tid; i4 < N2 / 4; i4 += 256) {
        int4 ev = ((const int4*)e_flat)[i4];
        int slot = i4 * 4;
#pragma unroll
        for (int j = 0; j < 4; ++j) {
            int ee = (j == 0) ? ev.x : (j == 1) ? ev.y : (j == 2) ? ev.z : ev.w;
            if (ee == e) {
                float p = p_flat[slot + j];
                int pos = atomicAdd(&cnt, 1);
                if (pos < 4096)
                    keys[pos] = ((unsigned long long)__float_as_uint(p) << 32) |
                                (unsigned long long)(0xFFFFFFFFu - (unsigned)(slot + j));
            }
        }
    }
    __syncthreads();
    const int n = cnt;

    if (n > CAPACITY) {
        int m = 2048;                    // n > 1126 -> m is 2048 or 4096
        while (m < n) m <<= 1;
        for (int i = tid; i < m; i += 256)
            if (i >= n) keys[i] = 0ull;
        __syncthreads();

        for (int k = 2; k <= m; k <<= 1) {
            for (int j = k >> 1; j > 0; j >>= 1) {
                for (int i = tid; i < m; i += 256) {
                    int ixj = i ^ j;
                    if (ixj > i) {
                        bool desc = ((i & k) == 0);
                        unsigned long long a = keys[i], b = keys[ixj];
                        bool sw = desc ? (a < b) : (a > b);
                        if (sw) { keys[i] = b; keys[ixj] = a; }
                    }
                }
                __syncthreads();
            }
        }
    }

    int lim = n < CAPACITY ? n : CAPACITY;
    for (int pos = tid; pos < lim; pos += 256) {
        unsigned long long key = keys[pos];
        unsigned slot = 0xFFFFFFFFu - (unsigned)(key & 0xFFFFFFFFull);
        float p = __uint_as_float((unsigned)(key >> 32));
        int token = (int)(slot >> 1);
        dispatch[(size_t)token * 64 + e] = 1.0f;
        combine [(size_t)token * 64 + e] = p;
    }
    if (tid == 0) counts[e] = n;
}

// ---------------- aux loss ----------------
__global__ void aux_kernel(const float* __restrict__ psum,
                           const int* __restrict__ counts,
                           float* __restrict__ out_aux) {
    int tid = threadIdx.x;   // 64 threads
    float v = (psum[tid] / (float)TOKENS) * ((float)counts[tid] / (float)N2);
    for (int off = 32; off > 0; off >>= 1) v += __shfl_down(v, off, 64);
    if (tid == 0) *out_aux = v * (float)NEXP;
}

extern "C" void kernel_launch(void* const* d_in, const int* in_sizes, int n_in,
                              void* d_out, int out_size, void* d_ws, size_t ws_size,
                              hipStream_t stream) {
    (void)in_sizes; (void)n_in; (void)out_size; (void)ws_size;

    const float* x = (const float*)d_in[0];
    const float* W = (const float*)d_in[1];

    float* out      = (float*)d_out;
    float* dispatch = out;                         // [32768*64]
    float* combine  = out + (size_t)TOKENS * NEXP; // [32768*64]
    float* probs    = out + (size_t)2 * TOKENS * NEXP;
    float* aux      = out + (size_t)3 * TOKENS * NEXP;

    char*  ws     = (char*)d_ws;
    float* part   = (float*)(ws + WS_PART);
    float* p_flat = (float*)(ws + WS_PFLAT);
    int*   e_flat = (int*)  (ws + WS_EFLAT);
    float* psum   = (float*)(ws + WS_PSUM);
    int*   counts = (int*)  (ws + WS_CNT);
    float* Wt     = (float*)(ws + WS_WT);

    zero_kernel<<<1024, 256, 0, stream>>>(dispatch, psum);
    wtrans_kernel<<<64, 256, 0, stream>>>(W, Wt);
    gemm_logits<<<1024, 128, 0, stream>>>(x, Wt, part);
    combine_kernel<<<256, 256, 0, stream>>>(part, probs, p_flat, e_flat, psum);
    expert_sort_kernel<<<64, 256, 0, stream>>>(p_flat, e_flat, dispatch, combine, counts);
    aux_kernel<<<1, 64, 0, stream>>>(psum, counts, aux);
}